// Round 1
// baseline (54.770 us; speedup 1.0000x reference)
//
#include <hip/hip_runtime.h>
#include <hip/hip_bf16.h>

typedef __bf16 bf16;
typedef __bf16 bf16x2 __attribute__((ext_vector_type(2)));
typedef __bf16 bf16x4 __attribute__((ext_vector_type(4)));
typedef __bf16 bf16x8 __attribute__((ext_vector_type(8)));
typedef float f32x4 __attribute__((ext_vector_type(4)));

#define NB 8
#define L_ 4096
#define C_ 512
#define KW 5
#define NS 8
#define BM 128
#define BK 32
#define KSTEPS (C_ / BK) /* 16 */

#define GLOAD_LDS16(g, l)                                                      \
  __builtin_amdgcn_global_load_lds(                                            \
      (const __attribute__((address_space(1))) void*)(g),                      \
      (__attribute__((address_space(3))) void*)(l), 16, 0, 0)

// ---------------------------------------------------------------------------
// prep: w_pw (fp32 [C_out][C_in]) -> bf16 copy; bias2[n] = b_pw[n] + sum_k b_dw[k]*w_pw[n][k]
// ---------------------------------------------------------------------------
__global__ __launch_bounds__(256) void prep_kernel(
    const float* __restrict__ w_pw, const float* __restrict__ b_dw,
    const float* __restrict__ b_pw, bf16* __restrict__ wbf,
    float* __restrict__ bias2) {
  const int n = blockIdx.x;   // 0..511
  const int t = threadIdx.x;  // 0..255
  float2 v = *(const float2*)(w_pw + n * C_ + 2 * t);
  bf16x2 hv;
  hv[0] = (bf16)v.x;
  hv[1] = (bf16)v.y;
  *(bf16x2*)(wbf + n * C_ + 2 * t) = hv;
  float2 bb = *(const float2*)(b_dw + 2 * t);
  float s = v.x * bb.x + v.y * bb.y;
#pragma unroll
  for (int off = 32; off; off >>= 1) s += __shfl_down(s, off, 64);
  __shared__ float part[4];
  if ((t & 63) == 0) part[t >> 6] = s;
  __syncthreads();
  if (t == 0) bias2[n] = b_pw[n] + part[0] + part[1] + part[2] + part[3];
}

// ---------------------------------------------------------------------------
// fused: segment-causal depthwise conv (computed on the fly into LDS as bf16)
//        + bf16 MFMA GEMM vs w_pw^T, fp32 epilogue with bias2.
// Grid: 256 blocks (M-tiles of 128 rows), 512 threads (8 waves: 2 M x 4 N).
// ---------------------------------------------------------------------------
__global__ __launch_bounds__(512, 2) void fused_dwconv_gemm(
    const float* __restrict__ x, const int* __restrict__ segb,
    const float* __restrict__ w_dw, const float* __restrict__ b_dw,
    const bf16* __restrict__ wbf, const float* __restrict__ bias2,
    float* __restrict__ out) {
  __shared__ bf16 Bs[2][C_ * BK];   // [n][k-chunk swizzled], 32 KB per buf
  __shared__ bf16 dws[2][BM][40];   // padded to 40 (80 B row) -> conflict-free b128
  __shared__ int segst[BM];

  const int t = threadIdx.x;
  const int lane = t & 63;
  const int wid = t >> 6;
  const int wm = wid >> 2;  // 0..1
  const int wn = wid & 3;   // 0..3

  const int tile = blockIdx.x;       // 0..255
  const int b = tile >> 5;           // L_/BM = 32 tiles per batch row
  const int l0 = (tile & 31) << 7;   // tile * 128

  // per-row segment start (segments are a contiguous partition of [0,L))
  if (t < BM) {
    int l = l0 + t;
    const int* sb = segb + b * NS * 2;
    int st = 0;
#pragma unroll
    for (int s = 0; s < NS; ++s) {
      int a0 = sb[2 * s], a1 = sb[2 * s + 1];
      if (l >= a0 && l < a1) st = a0;
    }
    segst[t] = st;
  }
  __syncthreads();

  // staging geometry: thread owns 2 rows x 4 channels per K-step
  const int c4 = t & 7;    // channel quad within BK
  const int rb = t >> 3;   // 0..63
  const int r0 = rb * 2;   // local row
  int nv0 = (l0 + r0) - segst[r0];
  if (nv0 > 4) nv0 = 4;
  int nv1 = (l0 + r0 + 1) - segst[r0 + 1];
  if (nv1 > 4) nv1 = 4;

  const long xrow = (long)(b * L_ + l0 + r0 - 4);
  const float* xbase = x + xrow * C_ + c4 * 4;
  const int wuni = t & ~63;  // wave-uniform chunk base

  f32x4 acc[4][8];
#pragma unroll
  for (int i = 0; i < 4; ++i)
#pragma unroll
    for (int j = 0; j < 8; ++j) acc[i][j] = (f32x4){0.f, 0.f, 0.f, 0.f};

  auto stage = [&](int kk, int p) {
    const int k0 = kk * BK;
    // ---- B tile via global_load_lds (pre-swizzled source, linear LDS dest)
#pragma unroll
    for (int i = 0; i < 4; ++i) {
      int q = i * 512 + t;  // linear 16B chunk id: row n = q>>2, chunk c = q&3
      int n = q >> 2, c = q & 3;
      int src = c ^ ((n >> 1) & 3);
      const bf16* g = wbf + n * C_ + k0 + src * 8;
      bf16* lp = (bf16*)Bs[p] + (i * 512 + wuni) * 8;  // +lane*16B by HW
      GLOAD_LDS16(g, lp);
    }
    // ---- x rows r0-4 .. r0+1 (float4, coalesced), zero left edge
    float4 v[6];
#pragma unroll
    for (int m = 0; m < 6; ++m) {
      long l = (long)l0 + r0 - 4 + m;
      if (l >= 0)
        v[m] = *(const float4*)(xbase + (long)m * C_ + k0);
      else
        v[m] = make_float4(0.f, 0.f, 0.f, 0.f);
    }
    // ---- w_dw rows c0..c0+3 (20 contiguous floats) + b_dw quad
    const int c0 = k0 + c4 * 4;
    float wf[20];
#pragma unroll
    for (int i = 0; i < 5; ++i)
      *(float4*)(wf + 4 * i) = *(const float4*)(w_dw + c0 * KW + 4 * i);
    const float4 bd = *(const float4*)(b_dw + c0);

    // ---- depthwise conv -> bf16 -> LDS
#pragma unroll
    for (int j = 0; j < 2; ++j) {
      const int nv = j ? nv1 : nv0;
      bf16x4 h;
#pragma unroll
      for (int i = 0; i < 4; ++i) {
        float a = (i == 0) ? bd.x : (i == 1) ? bd.y : (i == 2) ? bd.z : bd.w;
#pragma unroll
        for (int d = 0; d <= 4; ++d) {
          // tap d back: x row index m = j+4-d, weight w_dw[c][4-d]
          float wv = (d <= nv) ? wf[i * 5 + 4 - d] : 0.f;
          float xv = ((const float*)&v[j + 4 - d])[i];
          a = fmaf(wv, xv, a);
        }
        h[i] = (bf16)a;
      }
      *(bf16x4*)&dws[p][r0 + j][c4 * 4] = h;
    }
  };

  auto mma = [&](int p) {
    bf16x8 afr[4];
#pragma unroll
    for (int mf = 0; mf < 4; ++mf) {
      int row = wm * 64 + mf * 16 + (lane & 15);
      afr[mf] = *(const bf16x8*)&dws[p][row][(lane >> 4) * 8];
    }
#pragma unroll
    for (int nf = 0; nf < 8; ++nf) {
      int n = wn * 128 + nf * 16 + (lane & 15);
      int c = (lane >> 4) ^ ((n >> 1) & 3);
      bf16x8 bfr = *(const bf16x8*)((const bf16*)Bs[p] + n * 32 + c * 8);
#pragma unroll
      for (int mf = 0; mf < 4; ++mf)
        acc[mf][nf] = __builtin_amdgcn_mfma_f32_16x16x32_bf16(
            afr[mf], bfr, acc[mf][nf], 0, 0, 0);
    }
  };

  stage(0, 0);
#pragma unroll 1
  for (int kk = 0; kk < KSTEPS; ++kk) {
    __syncthreads();  // buf kk&1 ready (drains lgkm + vmcnt)
    if (kk + 1 < KSTEPS) stage(kk + 1, (kk + 1) & 1);
    mma(kk & 1);
  }

  // ---- epilogue: fp32 + bias2 (holds b_pw + w_pw.b_dw, computed fp32)
  const int col0 = wn * 128 + (lane & 15);
  float bia[8];
#pragma unroll
  for (int nf = 0; nf < 8; ++nf) bia[nf] = bias2[col0 + nf * 16];
  const int rb0 = l0 + wm * 64 + ((lane >> 4) << 2);
#pragma unroll
  for (int mf = 0; mf < 4; ++mf) {
#pragma unroll
    for (int i = 0; i < 4; ++i) {
      int row = rb0 + mf * 16 + i;
      float* o = out + (size_t)(b * L_ + row) * C_ + col0;
#pragma unroll
      for (int nf = 0; nf < 8; ++nf) o[nf * 16] = acc[mf][nf][i] + bia[nf];
    }
  }
}

extern "C" void kernel_launch(void* const* d_in, const int* in_sizes, int n_in,
                              void* d_out, int out_size, void* d_ws,
                              size_t ws_size, hipStream_t stream) {
  const float* x = (const float*)d_in[0];
  const int* segb = (const int*)d_in[1];     // [B][S][2] int32
  const float* w_dw = (const float*)d_in[2]; // [C][K]
  const float* b_dw = (const float*)d_in[3]; // [C]
  const float* w_pw = (const float*)d_in[4]; // [C_out][C_in]
  const float* b_pw = (const float*)d_in[5]; // [C]
  float* out = (float*)d_out;

  bf16* wbf = (bf16*)d_ws;                              // 512 KB
  float* bias2 = (float*)((char*)d_ws + C_ * C_ * 2);   // 2 KB

  prep_kernel<<<C_, 256, 0, stream>>>(w_pw, b_dw, b_pw, wbf, bias2);
  fused_dwconv_gemm<<<(NB * L_) / BM, 512, 0, stream>>>(x, segb, w_dw, b_dw,
                                                        wbf, bias2, out);
}